// Round 4
// baseline (1559.003 us; speedup 1.0000x reference)
//
#include <hip/hip_runtime.h>

// ---------------------------------------------------------------------------
// CMSFlipLinear: y = x @ W^T, W = ternary * per-128-group scales.
// Round 4: INT8 MFMA path. Ternary is EXACT in i8; x -> i8 per-row scale;
// i32 accumulation exact; per-group scale applied per K-tile (BK=128 = one
// group) as i32->f32 rescale; x row-scale folded into C-write.
// GEMM schedule = R2's verified race-free 8-phase map (same barriers, same
// vmcnt(6) points, same conflict-free 16-row read geometry), bytes not shorts.
// mfma_i32_16x16x64_i8, BM=BN=256, BK=128, 8 waves. M=8192, N=4096, K=4096.
// ---------------------------------------------------------------------------

typedef int   intx4 __attribute__((ext_vector_type(4)));
typedef float f32x4 __attribute__((ext_vector_type(4)));

constexpr int K  = 4096;
constexpr int N  = 4096;
constexpr int NG = 32;   // groups per output row = K/128

__device__ __forceinline__ unsigned short f2bf(float f) {
  unsigned u = __float_as_uint(f);
  u += 0x7FFFu + ((u >> 16) & 1u);
  return (unsigned short)(u >> 16);
}

__device__ __forceinline__ void gload_lds16(const void* gsrc, void* ldst) {
  const __attribute__((address_space(1))) unsigned* g =
      reinterpret_cast<const __attribute__((address_space(1))) unsigned*>(
          reinterpret_cast<uintptr_t>(gsrc));
  __attribute__((address_space(3))) unsigned* l =
      reinterpret_cast<__attribute__((address_space(3))) unsigned*>(
          reinterpret_cast<uintptr_t>(ldst));
  __builtin_amdgcn_global_load_lds(g, l, 16, 0, 0);
}

// ---- prep 1: x -> i8 with per-row scale (row stays in registers) -----------
__global__ __launch_bounds__(256) void quant_x_kernel(const float* __restrict__ x,
                                                      char* __restrict__ q,
                                                      float* __restrict__ sx) {
  const int row = blockIdx.x;
  const int tid = threadIdx.x;
  const float4* xr = reinterpret_cast<const float4*>(x + (long)row * K);
  float4 v[4];
  float am = 0.f;
#pragma unroll
  for (int j = 0; j < 4; ++j) {
    v[j] = xr[tid * 4 + j];
    am = fmaxf(am, fmaxf(fmaxf(fabsf(v[j].x), fabsf(v[j].y)),
                         fmaxf(fabsf(v[j].z), fabsf(v[j].w))));
  }
#pragma unroll
  for (int off = 32; off > 0; off >>= 1)
    am = fmaxf(am, __shfl_xor(am, off));
  __shared__ float wmax[4];
  if ((tid & 63) == 0) wmax[tid >> 6] = am;
  __syncthreads();
  am = fmaxf(fmaxf(wmax[0], wmax[1]), fmaxf(wmax[2], wmax[3]));
  const float inv = am > 0.f ? 127.f / am : 0.f;
  int t[16];
#pragma unroll
  for (int j = 0; j < 4; ++j) {
    t[j * 4 + 0] = (int)rintf(v[j].x * inv);
    t[j * 4 + 1] = (int)rintf(v[j].y * inv);
    t[j * 4 + 2] = (int)rintf(v[j].z * inv);
    t[j * 4 + 3] = (int)rintf(v[j].w * inv);
  }
  int4 o;
  o.x = (t[0] & 255) | ((t[1] & 255) << 8) | ((t[2] & 255) << 16) | ((t[3] & 255) << 24);
  o.y = (t[4] & 255) | ((t[5] & 255) << 8) | ((t[6] & 255) << 16) | ((t[7] & 255) << 24);
  o.z = (t[8] & 255) | ((t[9] & 255) << 8) | ((t[10] & 255) << 16) | ((t[11] & 255) << 24);
  o.w = (t[12] & 255) | ((t[13] & 255) << 8) | ((t[14] & 255) << 16) | ((t[15] & 255) << 24);
  reinterpret_cast<int4*>(q + (long)row * K)[tid] = o;
  if (tid == 0) sx[row] = am * (1.f / 127.f);
}

// ---- prep 2: ternary int32 -> i8 -------------------------------------------
__global__ void pack_w_kernel(const int* __restrict__ w, char* __restrict__ o,
                              long n16) {
  long t = (long)blockIdx.x * blockDim.x + threadIdx.x;
  if (t >= n16) return;
  const int4* src = reinterpret_cast<const int4*>(w + t * 16);
  int4 a = src[0], b = src[1], c = src[2], d = src[3];
  int4 r;
  r.x = (a.x & 255) | ((a.y & 255) << 8) | ((a.z & 255) << 16) | ((a.w & 255) << 24);
  r.y = (b.x & 255) | ((b.y & 255) << 8) | ((b.z & 255) << 16) | ((b.w & 255) << 24);
  r.z = (c.x & 255) | ((c.y & 255) << 8) | ((c.z & 255) << 16) | ((c.w & 255) << 24);
  r.w = (d.x & 255) | ((d.y & 255) << 8) | ((d.z & 255) << 16) | ((d.w & 255) << 24);
  reinterpret_cast<int4*>(o)[t] = r;
}

// ---- prep 3: scales [o][g] f32 -> transposed [g][o] bf16 -------------------
__global__ void cvt_s_kernel(const float* __restrict__ s,
                             unsigned short* __restrict__ o) {
  int t = blockIdx.x * 256 + threadIdx.x;  // 131072 = 32*4096
  int oo = t & (N - 1);
  int g = t >> 12;
  o[t] = f2bf(s[(long)oo * NG + g]);
}

// ---------------------------------------------------------------------------
// GEMM LDS (bytes): a0 [0,32768) | b0 | a1 | b1 | sc [131072,147456)
// Tile = 256 rows x 128 k-bytes. Swizzle: byte = row*128 + (slot ^ ((row&7)<<4)),
// applied on ds_read AND on the global source of linear-dest global_load_lds.
// Read: row = base + (l&15), slot = ks*64 + (l>>4)*16 -> 16 rows x 8 slots,
// XOR by row&7 -> 2 lanes/bank-group = conflict-free (R2-verified geometry).
// ---------------------------------------------------------------------------

__device__ __forceinline__ intx4 ldfrag(const char* region, int row, int slot) {
  return *reinterpret_cast<const intx4*>(region + row * 128 +
                                         (slot ^ ((row & 7) << 4)));
}

// Stage one half-tile (128 rows x 128 B = 16 KiB): 2 global_load_lds_dwordx4
// per thread; LDS dest linear, global source col pre-swizzled.
__device__ __forceinline__ void stage_half(const char* gmat, char* lregion,
                                           int k0, int h, int wid, int l) {
#pragma unroll
  for (int load = 0; load < 2; ++load) {
    const int row = h * 128 + load * 64 + wid * 8 + (l >> 3);
    const int col = ((l & 7) ^ ((l >> 3) & 7)) << 4;
    const char* g = gmat + (long)row * K + k0 + col;
    char* ldst = lregion + h * 16384 + load * 8192 + wid * 1024;  // + lane*16 by HW
    gload_lds16(g, ldst);
  }
}

template <int Q>
__device__ __forceinline__ void loadApair(intx4 (&afr)[2][2], const char* ar,
                                          int wr, int rlo, int kq) {
#pragma unroll
  for (int mi = 0; mi < 2; ++mi)
#pragma unroll
    for (int ks = 0; ks < 2; ++ks)
      afr[mi][ks] = ldfrag(ar, wr * 128 + (2 * Q + mi) * 16 + rlo, ks * 64 + kq * 16);
}

__device__ __forceinline__ void loadBall(intx4 (&bfr)[4][2], const char* br,
                                         int wc, int rlo, int kq) {
#pragma unroll
  for (int nt = 0; nt < 4; ++nt)
#pragma unroll
    for (int ks = 0; ks < 2; ++ks)
      bfr[nt][ks] = ldfrag(br, wc * 64 + nt * 16 + rlo, ks * 64 + kq * 16);
}

// per-tile weight scales: sc[T][col] bf16, broadcast across kq groups
__device__ __forceinline__ void loadScales(float (&swf)[4], const char* sc,
                                           int T, int wc, int rlo) {
#pragma unroll
  for (int nt = 0; nt < 4; ++nt) {
    unsigned short v = *reinterpret_cast<const unsigned short*>(
        sc + T * 512 + (wc * 64 + nt * 16 + rlo) * 2);
    swf[nt] = __uint_as_float((unsigned)v << 16);
  }
}

template <int Q>
__device__ __forceinline__ void mmaQ(f32x4 (&facc)[8][4], intx4 (&afr)[2][2],
                                     intx4 (&bfr)[4][2], const float (&swf)[4]) {
  __builtin_amdgcn_s_setprio(1);
#pragma unroll
  for (int mi = 0; mi < 2; ++mi)
#pragma unroll
    for (int nt = 0; nt < 4; ++nt) {
      intx4 t = {0, 0, 0, 0};
      t = __builtin_amdgcn_mfma_i32_16x16x64_i8(afr[mi][0], bfr[nt][0], t, 0, 0, 0);
      t = __builtin_amdgcn_mfma_i32_16x16x64_i8(afr[mi][1], bfr[nt][1], t, 0, 0, 0);
#pragma unroll
      for (int r = 0; r < 4; ++r)
        facc[2 * Q + mi][nt][r] += (float)t[r] * swf[nt];
    }
  __builtin_amdgcn_s_setprio(0);
}

#define FENCE asm volatile("" ::: "memory")
#define BAR                       \
  do {                            \
    __builtin_amdgcn_s_barrier(); \
    FENCE;                        \
  } while (0)
#define LGKM0  asm volatile("s_waitcnt lgkmcnt(0)" ::: "memory")
#define VMCNT6 asm volatile("s_waitcnt vmcnt(6)" ::: "memory")
#define VMCNT0 asm volatile("s_waitcnt vmcnt(0)" ::: "memory")

// 256x256x128-tile i8 GEMM, 8 waves (2Mx4N), per-wave 128x64 out.
// Phase/stage/vmcnt map identical to R2 (verified race-free), K-offsets x2.
__global__ __launch_bounds__(512, 2) void gemm8p(
    const char* __restrict__ A, const char* __restrict__ B,
    const unsigned short* __restrict__ SWT, const float* __restrict__ SX,
    float* __restrict__ C) {
  __shared__ char lds[147456];  // 144 KiB
  const int tid = threadIdx.x;
  const int wid = tid >> 6, l = tid & 63;
  const int wr = wid >> 2, wc = wid & 3;
  const int rlo = l & 15, kq = l >> 4;

  // T1: bijective XCD swizzle (512 blocks, 512%8==0)
  const int wg = blockIdx.x;
  const int swz = (wg & 7) * 64 + (wg >> 3);
  const long brow = (long)(swz >> 4) * 256;  // 32 M-tiles
  const long bcol = (long)(swz & 15) * 256;  // 16 N-tiles

  const char* gA = A + brow * K;
  const char* gB = B + bcol * K;
  char* a0 = lds;
  char* b0 = lds + 32768;
  char* a1 = lds + 65536;
  char* b1 = lds + 98304;
  char* sc = lds + 131072;  // [32 g][512 B] block's weight scales (bf16)

  // prologue: scale slab (2 loads/wave), then b0,a0 (tile0) + b1,a1-lo (tile1)
#pragma unroll
  for (int j = 0; j < 2; ++j) {
    const int gp = wid * 2 + j;  // 0..15, each covers 2 g-rows
    const unsigned short* src =
        SWT + (size_t)(gp * 2 + (l >> 5)) * N + bcol + (l & 31) * 8;
    gload_lds16(src, sc + gp * 1024);
  }
  stage_half(gB, b0, 0, 0, wid, l);
  stage_half(gB, b0, 0, 1, wid, l);
  stage_half(gA, a0, 0, 0, wid, l);
  stage_half(gA, a0, 0, 1, wid, l);
  stage_half(gB, b1, 128, 0, wid, l);
  stage_half(gB, b1, 128, 1, wid, l);
  stage_half(gA, a1, 128, 0, wid, l);
  VMCNT6;  // drains sc,b0,a0; leaves b1(4)+a1-lo(2) in flight
  BAR;

  f32x4 facc[8][4] = {};
  intx4 afr[2][2], bfr[4][2];
  float swf[4];

#pragma unroll 1
  for (int it = 0; it < 15; ++it) {
    const int kt1 = (2 * it + 1) * 128, kt2 = kt1 + 128, kt3 = kt2 + 128;
    // ---- tile 2it (buf0) ----
    loadBall(bfr, b0, wc, rlo, kq);
    loadApair<0>(afr, a0, wr, rlo, kq);
    loadScales(swf, sc, 2 * it, wc, rlo);
    stage_half(gA, a1, kt1, 1, wid, l);
    BAR; LGKM0;
    mmaQ<0>(facc, afr, bfr, swf);
    BAR;
    loadApair<1>(afr, a0, wr, rlo, kq);
    stage_half(gB, b0, kt2, 0, wid, l);
    BAR; LGKM0;
    mmaQ<1>(facc, afr, bfr, swf);
    BAR;
    loadApair<2>(afr, a0, wr, rlo, kq);
    stage_half(gB, b0, kt2, 1, wid, l);
    BAR; LGKM0;
    mmaQ<2>(facc, afr, bfr, swf);
    BAR;
    loadApair<3>(afr, a0, wr, rlo, kq);
    stage_half(gA, a0, kt2, 0, wid, l);
    BAR; LGKM0;
    mmaQ<3>(facc, afr, bfr, swf);
    VMCNT6;  // tile 2it+1 fully landed
    BAR;
    // ---- tile 2it+1 (buf1) ----
    loadBall(bfr, b1, wc, rlo, kq);
    loadApair<0>(afr, a1, wr, rlo, kq);
    loadScales(swf, sc, 2 * it + 1, wc, rlo);
    stage_half(gA, a0, kt2, 1, wid, l);
    BAR; LGKM0;
    mmaQ<0>(facc, afr, bfr, swf);
    BAR;
    loadApair<1>(afr, a1, wr, rlo, kq);
    stage_half(gB, b1, kt3, 0, wid, l);
    BAR; LGKM0;
    mmaQ<1>(facc, afr, bfr, swf);
    BAR;
    loadApair<2>(afr, a1, wr, rlo, kq);
    stage_half(gB, b1, kt3, 1, wid, l);
    BAR; LGKM0;
    mmaQ<2>(facc, afr, bfr, swf);
    BAR;
    loadApair<3>(afr, a1, wr, rlo, kq);
    stage_half(gA, a1, kt3, 0, wid, l);
    BAR; LGKM0;
    mmaQ<3>(facc, afr, bfr, swf);
    VMCNT6;  // tile 2it+2 fully landed
    BAR;
  }

  // ---- epilogue: tiles 30 (buf0) + 31 (buf1) ----
  loadBall(bfr, b0, wc, rlo, kq);
  loadApair<0>(afr, a0, wr, rlo, kq);
  loadScales(swf, sc, 30, wc, rlo);
  stage_half(gA, a1, 31 * 128, 1, wid, l);  // completes tile 31
  BAR; LGKM0;
  mmaQ<0>(facc, afr, bfr, swf);
  BAR;
  loadApair<1>(afr, a0, wr, rlo, kq);
  BAR; LGKM0;
  mmaQ<1>(facc, afr, bfr, swf);
  BAR;
  loadApair<2>(afr, a0, wr, rlo, kq);
  BAR; LGKM0;
  mmaQ<2>(facc, afr, bfr, swf);
  BAR;
  loadApair<3>(afr, a0, wr, rlo, kq);
  BAR; LGKM0;
  mmaQ<3>(facc, afr, bfr, swf);
  VMCNT0;  // drain tile 31 leftovers
  BAR;
  // tile 31: no more LDS writers
  loadBall(bfr, b1, wc, rlo, kq);
  loadScales(swf, sc, 31, wc, rlo);
  loadApair<0>(afr, a1, wr, rlo, kq);
  LGKM0;
  mmaQ<0>(facc, afr, bfr, swf);
  loadApair<1>(afr, a1, wr, rlo, kq);
  mmaQ<1>(facc, afr, bfr, swf);
  loadApair<2>(afr, a1, wr, rlo, kq);
  mmaQ<2>(facc, afr, bfr, swf);
  loadApair<3>(afr, a1, wr, rlo, kq);
  mmaQ<3>(facc, afr, bfr, swf);

  // C-write: col = lane&15, row = kq*4 + r; apply x row-scale here.
  const long crow0 = brow + wr * 128 + kq * 4;
  const long ccol = bcol + wc * 64 + rlo;
#pragma unroll
  for (int mi = 0; mi < 8; ++mi) {
    const float4 sx4 = *reinterpret_cast<const float4*>(SX + crow0 + mi * 16);
#pragma unroll
    for (int nt = 0; nt < 4; ++nt) {
      float* cp = C + (crow0 + mi * 16) * (long)N + ccol + nt * 16;
      cp[0 * N] = facc[mi][nt][0] * sx4.x;
      cp[1 * N] = facc[mi][nt][1] * sx4.y;
      cp[2 * N] = facc[mi][nt][2] * sx4.z;
      cp[3 * N] = facc[mi][nt][3] * sx4.w;
    }
  }
}

// ---- fallback (only if workspace too small): naive fp32 --------------------
__global__ void fallback_kernel(const float* __restrict__ x,
                                const int* __restrict__ t,
                                const float* __restrict__ s,
                                float* __restrict__ y) {
  int n = blockIdx.x * 256 + threadIdx.x;
  int m = blockIdx.y;
  const int* tr = t + (long)n * K;
  const float* xr = x + (long)m * K;
  float acc = 0.f;
  for (int g = 0; g < K / 128; ++g) {
    float scv = s[n * (K / 128) + g];
    float part = 0.f;
#pragma unroll 4
    for (int k = g * 128; k < g * 128 + 128; ++k)
      part += xr[k] * (float)tr[k];
    acc += part * scv;
  }
  y[(long)m * N + n] = acc;
}

extern "C" void kernel_launch(void* const* d_in, const int* in_sizes, int n_in,
                              void* d_out, int out_size, void* d_ws,
                              size_t ws_size, hipStream_t stream) {
  const float* x = (const float*)d_in[0];
  const int* tern = (const int*)d_in[1];
  const float* scales = (const float*)d_in[2];
  float* out = (float*)d_out;

  const long M = (long)in_sizes[0] / K;  // 8192
  const size_t offW = (size_t)M * K;                 // A_i8: 32 MiB
  const size_t offS = offW + (size_t)N * K;          // W_i8: 16 MiB
  const size_t offX = offS + (size_t)NG * N * 2;     // sw_t bf16: 256 KiB
  const size_t need = offX + (size_t)M * 4;          // s_x f32

  if (ws_size >= need && (M % 256) == 0) {
    char* Aq = (char*)d_ws;
    char* Wq = (char*)d_ws + offW;
    unsigned short* SWT = (unsigned short*)((char*)d_ws + offS);
    float* SX = (float*)((char*)d_ws + offX);

    quant_x_kernel<<<(unsigned)M, 256, 0, stream>>>(x, Aq, SX);
    const long n16 = (long)N * K / 16;
    pack_w_kernel<<<(unsigned)((n16 + 255) / 256), 256, 0, stream>>>(tern, Wq, n16);
    cvt_s_kernel<<<(unsigned)(NG * N / 256), 256, 0, stream>>>(scales, SWT);

    const unsigned nblk = (unsigned)((M / 256) * (N / 256));  // 512
    gemm8p<<<nblk, 512, 0, stream>>>(Aq, Wq, SWT, SX, out);
  } else {
    dim3 grid(N / 256, (unsigned)M);
    fallback_kernel<<<grid, 256, 0, stream>>>(x, tern, scales, out);
  }
}

// Round 5
// 277.978 us; speedup vs baseline: 5.6084x; 5.6084x over previous
//
#include <hip/hip_runtime.h>

// ---------------------------------------------------------------------------
// CMSFlipLinear: y = x @ W^T, W = ternary * per-128-group scales.
// Round 5: R2 base (256x256 8-phase bf16, verified 240us) + rolling A-fragment
// register double-buffer + counted lgkmcnt(4) waits (lgkm analog of T4) +
// rebalanced race-free stage map: P1:a1(lo+hi), P2/P3:b0, P5/P6:a0, P7/P8:b1,
// vmcnt(4) at P4/P8. FIFO re-verified: P4 drains {prev-b1, a1} before P5 reads;
// P8 drains {b0,a0} before next-P1 reads. Stage-vs-read races: every staged
// region's last ds_read drains at an explicit counted wait >=1 barrier before
// the stage issues (sched_barrier(0) pins B+q0 | q1 issue order in P1/P5).
// M=8192, N=4096, K=4096.
// ---------------------------------------------------------------------------

using bf16x8 = __attribute__((ext_vector_type(8))) short;
using f32x4  = __attribute__((ext_vector_type(4))) float;
using u16x4  = __attribute__((ext_vector_type(4))) unsigned short;
using u16x8  = __attribute__((ext_vector_type(8))) unsigned short;

constexpr int K = 4096;
constexpr int N = 4096;

__device__ __forceinline__ unsigned short f2bf(float f) {
  unsigned u = __float_as_uint(f);
  u += 0x7FFFu + ((u >> 16) & 1u);
  return (unsigned short)(u >> 16);
}

__device__ __forceinline__ void gload_lds16(const void* gsrc, void* ldst) {
  const __attribute__((address_space(1))) unsigned* g =
      reinterpret_cast<const __attribute__((address_space(1))) unsigned*>(
          reinterpret_cast<uintptr_t>(gsrc));
  __attribute__((address_space(3))) unsigned* l =
      reinterpret_cast<__attribute__((address_space(3))) unsigned*>(
          reinterpret_cast<uintptr_t>(ldst));
  __builtin_amdgcn_global_load_lds(g, l, 16, 0, 0);
}

// ---- prep 1: x fp32 -> bf16 ------------------------------------------------
__global__ void cvt_x_kernel(const float* __restrict__ x,
                             unsigned short* __restrict__ o, long n4) {
  long t = (long)blockIdx.x * blockDim.x + threadIdx.x;
  if (t >= n4) return;
  float4 v = reinterpret_cast<const float4*>(x)[t];
  u16x4 r = {f2bf(v.x), f2bf(v.y), f2bf(v.z), f2bf(v.w)};
  reinterpret_cast<u16x4*>(o)[t] = r;
}

// ---- prep 2: W = ternary * scales -> bf16 ---------------------------------
__global__ void dequant_kernel(const int* __restrict__ w,
                               const float* __restrict__ s,
                               unsigned short* __restrict__ o, long n8) {
  long t = (long)blockIdx.x * blockDim.x + threadIdx.x;
  if (t >= n8) return;
  long e = t * 8;
  float sc = s[e >> 7];
  int4 a = reinterpret_cast<const int4*>(w + e)[0];
  int4 b = reinterpret_cast<const int4*>(w + e)[1];
  u16x8 r = {f2bf((float)a.x * sc), f2bf((float)a.y * sc),
             f2bf((float)a.z * sc), f2bf((float)a.w * sc),
             f2bf((float)b.x * sc), f2bf((float)b.y * sc),
             f2bf((float)b.z * sc), f2bf((float)b.w * sc)};
  *reinterpret_cast<u16x8*>(o + e) = r;
}

// ---------------------------------------------------------------------------
// LDS layout (shorts): a0 [0,16384) | b0 [16384,32768) | a1 [32768,49152)
//                      | b1 [49152,65536).
// Swizzle (shorts): idx = row*64 + (col ^ ((row&7)<<3)). Applied on ds_read
// AND on the global source of the linear-dest global_load_lds (rule #21).
// R2-verified: 0 bank conflicts.
// ---------------------------------------------------------------------------

__device__ __forceinline__ bf16x8 ldfrag(const short* region, int row, int col) {
  return *reinterpret_cast<const bf16x8*>(region + row * 64 +
                                          (col ^ ((row & 7) << 3)));
}

__device__ __forceinline__ void stage_half(const short* gmat, short* lregion,
                                           int k0, int h, int wid, int l) {
#pragma unroll
  for (int load = 0; load < 2; ++load) {
    const int row = h * 128 + load * 64 + wid * 8 + (l >> 3);
    const int col = ((l & 7) ^ (l >> 3)) << 3;  // inverse-swizzled source col
    const short* g = gmat + (long)row * K + k0 + col;
    short* ldst = lregion + h * 8192 + load * 4096 + wid * 512;  // +lane*16B HW
    gload_lds16(g, ldst);
  }
}

// A fragments for quadrant Q (rows wr*128 + Q*32 .. +31): 2 m-frags x 2 kk.
template <int Q>
__device__ __forceinline__ void loadAq(bf16x8 (&dst)[2][2], const short* ar,
                                       int wr, int rlo, int kq) {
#pragma unroll
  for (int mi = 0; mi < 2; ++mi)
#pragma unroll
    for (int kk = 0; kk < 2; ++kk)
      dst[mi][kk] = ldfrag(ar, wr * 128 + Q * 32 + mi * 16 + rlo,
                           kk * 32 + kq * 8);
}

__device__ __forceinline__ void loadB(bf16x8 (&bfr)[4][2], const short* br,
                                      int wc, int rlo, int kq) {
#pragma unroll
  for (int ni = 0; ni < 4; ++ni)
#pragma unroll
    for (int kk = 0; kk < 2; ++kk)
      bfr[ni][kk] = ldfrag(br, wc * 64 + ni * 16 + rlo, kk * 32 + kq * 8);
}

template <int Q>
__device__ __forceinline__ void mmaSet(f32x4 (&acc)[8][4], bf16x8 (&a)[2][2],
                                       bf16x8 (&bfr)[4][2]) {
  __builtin_amdgcn_s_setprio(1);
#pragma unroll
  for (int mi = 0; mi < 2; ++mi)
#pragma unroll
    for (int ni = 0; ni < 4; ++ni)
#pragma unroll
      for (int kk = 0; kk < 2; ++kk)
        acc[2 * Q + mi][ni] = __builtin_amdgcn_mfma_f32_16x16x32_bf16(
            a[mi][kk], bfr[ni][kk], acc[2 * Q + mi][ni], 0, 0, 0);
  __builtin_amdgcn_s_setprio(0);
}

#define FENCE asm volatile("" ::: "memory")
#define BAR                       \
  do {                            \
    __builtin_amdgcn_s_barrier(); \
    FENCE;                        \
  } while (0)
#define LGKM0  asm volatile("s_waitcnt lgkmcnt(0)" ::: "memory")
#define LGKM4  asm volatile("s_waitcnt lgkmcnt(4)" ::: "memory")
#define VMCNT4 asm volatile("s_waitcnt vmcnt(4)" ::: "memory")
#define VMCNT0 asm volatile("s_waitcnt vmcnt(0)" ::: "memory")
#define SB0    __builtin_amdgcn_sched_barrier(0)

// ---- 256x256 8-phase GEMM: C[M][N] = A[M][K] * B[N][K]^T -------------------
// 8 waves (2M x 4N), per-wave 128x64, acc[8][4] f32x4. Rolling A-sets:
// aE holds quadrants 0,2; aO holds 1,3. Reads flow one phase ahead of use.
__global__ __launch_bounds__(512) void gemm8p(const short* __restrict__ A,
                                              const short* __restrict__ B,
                                              float* __restrict__ C) {
  __shared__ short lds[65536];  // 128 KiB
  const int tid = threadIdx.x;
  const int wid = tid >> 6, l = tid & 63;
  const int wr = wid >> 2, wc = wid & 3;
  const int rlo = l & 15, kq = l >> 4;

  // T1: bijective XCD swizzle (512 blocks, 512%8==0)
  const int wg = blockIdx.x;
  const int swz = (wg & 7) * 64 + (wg >> 3);
  const long brow = (long)(swz >> 4) * 256;  // 32 M-tiles
  const long bcol = (long)(swz & 15) * 256;  // 16 N-tiles

  const short* gA = A + brow * K;
  const short* gB = B + bcol * K;
  short* a0 = lds;
  short* b0 = lds + 16384;
  short* a1 = lds + 32768;
  short* b1 = lds + 49152;

  // prologue: buf0@t0 (b0,a0) + b1@t1.  a1@t1 comes at iter0-P1.
  stage_half(gB, b0, 0, 0, wid, l);
  stage_half(gB, b0, 0, 1, wid, l);
  stage_half(gA, a0, 0, 0, wid, l);
  stage_half(gA, a0, 0, 1, wid, l);
  stage_half(gB, b1, 64, 0, wid, l);
  stage_half(gB, b1, 64, 1, wid, l);
  VMCNT4;  // drain b0,a0; b1 (4 loads) in flight
  BAR;

  f32x4 acc[8][4] = {};
  bf16x8 aE[2][2], aO[2][2], bfr[4][2];

#pragma unroll 1
  for (int it = 0; it < 31; ++it) {
    const int kt1 = (2 * it + 1) * 64, kt2 = kt1 + 64, kt3 = kt2 + 64;
    // ================= tile 2it (buf0) =================
    // P1: reads B+q0 | q1 (order pinned); stage a1@kt1 both halves
    loadB(bfr, b0, wc, rlo, kq);
    loadAq<0>(aE, a0, wr, rlo, kq);
    SB0;  // pin issue order: {B,q0} before q1 (counted-wait correctness)
    loadAq<1>(aO, a0, wr, rlo, kq);
    stage_half(gA, a1, kt1, 0, wid, l);
    stage_half(gA, a1, kt1, 1, wid, l);
    BAR; LGKM4; SB0;   // B+q0 done (q1 may be in flight)
    mmaSet<0>(acc, aE, bfr);
    BAR;
    // P2: read q2; stage b0-lo@kt2 (b0's B-reads drained at P1 wait)
    loadAq<2>(aE, a0, wr, rlo, kq);
    stage_half(gB, b0, kt2, 0, wid, l);
    BAR; LGKM4; SB0;   // q1 done
    mmaSet<1>(acc, aO, bfr);
    BAR;
    // P3: read q3; stage b0-hi@kt2
    loadAq<3>(aO, a0, wr, rlo, kq);
    stage_half(gB, b0, kt2, 1, wid, l);
    BAR; LGKM4; SB0;   // q2 done
    mmaSet<2>(acc, aE, bfr);
    BAR;
    // P4: no reads/stages; q3 then publish buf1
    LGKM0; SB0;        // q3 done
    mmaSet<3>(acc, aO, bfr);
    VMCNT4;            // drains prev-b1(4) + a1@kt1(4); b0@kt2 in flight
    BAR;
    // ================= tile 2it+1 (buf1) =================
    // P5: reads B+q0 | q1; stage a0-lo@kt2 (a0 reads drained at P4 LGKM0)
    loadB(bfr, b1, wc, rlo, kq);
    loadAq<0>(aE, a1, wr, rlo, kq);
    SB0;
    loadAq<1>(aO, a1, wr, rlo, kq);
    stage_half(gA, a0, kt2, 0, wid, l);
    BAR; LGKM4; SB0;
    mmaSet<0>(acc, aE, bfr);
    BAR;
    // P6: read q2; stage a0-hi@kt2
    loadAq<2>(aE, a1, wr, rlo, kq);
    stage_half(gA, a0, kt2, 1, wid, l);
    BAR; LGKM4; SB0;
    mmaSet<1>(acc, aO, bfr);
    BAR;
    // P7: read q3; stage b1-lo@kt3 (b1's B-reads drained at P5 wait)
    loadAq<3>(aO, a1, wr, rlo, kq);
    stage_half(gB, b1, kt3, 0, wid, l);
    BAR; LGKM4; SB0;
    mmaSet<2>(acc, aE, bfr);
    BAR;
    // P8: stage b1-hi@kt3; q3; publish buf0
    stage_half(gB, b1, kt3, 1, wid, l);
    LGKM0; SB0;
    mmaSet<3>(acc, aO, bfr);
    VMCNT4;            // drains b0@kt2(4) + a0@kt2(4); b1@kt3 in flight
    BAR;
  }

  // ---- epilogue: tiles 62 (buf0) + 63 (buf1) ----
  {
    // P1e: stage a1@4032 both halves (last stages anywhere)
    loadB(bfr, b0, wc, rlo, kq);
    loadAq<0>(aE, a0, wr, rlo, kq);
    SB0;
    loadAq<1>(aO, a0, wr, rlo, kq);
    stage_half(gA, a1, 4032, 0, wid, l);
    stage_half(gA, a1, 4032, 1, wid, l);
    BAR; LGKM4; SB0;
    mmaSet<0>(acc, aE, bfr);
    BAR;
    loadAq<2>(aE, a0, wr, rlo, kq);
    BAR; LGKM4; SB0;
    mmaSet<1>(acc, aO, bfr);
    BAR;
    loadAq<3>(aO, a0, wr, rlo, kq);
    BAR; LGKM4; SB0;
    mmaSet<2>(acc, aE, bfr);
    BAR;
    LGKM0; SB0;
    mmaSet<3>(acc, aO, bfr);
    VMCNT0;  // drain b1@4032(4) + a1@4032(4)
    BAR;
    // tile 63: no LDS writers remain; compiler auto-waits cover reads
    loadB(bfr, b1, wc, rlo, kq);
    loadAq<0>(aE, a1, wr, rlo, kq);
    loadAq<1>(aO, a1, wr, rlo, kq);
    mmaSet<0>(acc, aE, bfr);
    loadAq<2>(aE, a1, wr, rlo, kq);
    mmaSet<1>(acc, aO, bfr);
    loadAq<3>(aO, a1, wr, rlo, kq);
    mmaSet<2>(acc, aE, bfr);
    mmaSet<3>(acc, aO, bfr);
  }

  // C-write: col = lane&15, row = (lane>>4)*4 + reg (m89-verified)
  float* Cw = C + (brow + wr * 128 + kq * 4) * (long)N + bcol + wc * 64 + rlo;
#pragma unroll
  for (int mi = 0; mi < 8; ++mi)
#pragma unroll
    for (int ni = 0; ni < 4; ++ni)
#pragma unroll
      for (int r = 0; r < 4; ++r)
        Cw[(long)(mi * 16 + r) * N + ni * 16] = acc[mi][ni][r];
}

// ---- fallback (only if workspace too small): naive fp32 --------------------
__global__ void fallback_kernel(const float* __restrict__ x,
                                const int* __restrict__ t,
                                const float* __restrict__ s,
                                float* __restrict__ y) {
  int n = blockIdx.x * 256 + threadIdx.x;
  int m = blockIdx.y;
  const int* tr = t + (long)n * K;
  const float* xr = x + (long)m * K;
  float acc = 0.f;
  for (int g = 0; g < K / 128; ++g) {
    float sc = s[n * (K / 128) + g];
    float part = 0.f;
#pragma unroll 4
    for (int k = g * 128; k < g * 128 + 128; ++k)
      part += xr[k] * (float)tr[k];
    acc += part * sc;
  }
  y[(long)m * N + n] = acc;
}

extern "C" void kernel_launch(void* const* d_in, const int* in_sizes, int n_in,
                              void* d_out, int out_size, void* d_ws,
                              size_t ws_size, hipStream_t stream) {
  const float* x = (const float*)d_in[0];
  const int* tern = (const int*)d_in[1];
  const float* scales = (const float*)d_in[2];
  float* out = (float*)d_out;

  const long M = (long)in_sizes[0] / K;  // 8192
  const size_t needA = (size_t)M * K * sizeof(short);  // 64 MiB
  const size_t needB = (size_t)N * K * sizeof(short);  // 32 MiB

  if (ws_size >= needA + needB && (M % 256) == 0) {
    short* Abf = (short*)d_ws;
    short* Bbf = (short*)((char*)d_ws + needA);

    long n4 = M * K / 4;
    cvt_x_kernel<<<(unsigned)((n4 + 255) / 256), 256, 0, stream>>>(
        x, (unsigned short*)Abf, n4);

    long n8 = (long)N * K / 8;
    dequant_kernel<<<(unsigned)((n8 + 255) / 256), 256, 0, stream>>>(
        tern, scales, (unsigned short*)Bbf, n8);

    const unsigned nblk = (unsigned)((M / 256) * (N / 256));  // 512
    gemm8p<<<nblk, 512, 0, stream>>>(Abf, Bbf, out);
  } else {
    dim3 grid(N / 256, (unsigned)M);
    fallback_kernel<<<grid, 256, 0, stream>>>(x, tern, scales, out);
  }
}